// Round 5
// baseline (111.037 us; speedup 1.0000x reference)
//
#include <hip/hip_runtime.h>

// DeformConv2D b=4,c=128,H=W=64,outc=128,KS=3,PAD=1,N=9
// out[(b,i,j),o] = sum_ck W[o][ck] * A[ck][(b,i,j)], ck = tap*128 + c, K=1152
// Stage 1: x NCHW fp32 -> x_t (b,hw,c) bf16
// Stage 2: weight -> MFMA A-fragment layout wfrag[ot][ks][lane][8] bf16
// Stage 3: block = 32 px x 64 o (512 thr, 8 waves; wave = 16o x 16px, 1 acc).
//          Grid 1024 (= b4*i64*jh2*oh2) -> 4 blocks/CU -> 32 waves/CU.
//          3 tap-chunks: {bilinear stage -> LDS, 12 MFMA K-steps}.

typedef __bf16  v8bf16 __attribute__((ext_vector_type(8)));
typedef __bf16  bf16x2 __attribute__((ext_vector_type(2)));
typedef float   f32x4  __attribute__((ext_vector_type(4)));
typedef unsigned short ushort4v __attribute__((ext_vector_type(4)));
typedef _Float16 half4v __attribute__((ext_vector_type(4)));

#define CIN  128
#define NPT  9
#define KTOT 1152
#define OC   128
#define PX   32
#define NDESC (NPT * PX)   // 288
#define KSTEPS 36          // total K-steps of 32
#define KSC  12            // K-steps per tap-chunk (3 taps = K 384)
#define LDBc 392           // Bt row stride bf16 (784B; b128 reads 2-way = free)

// ---------- x NCHW fp32 -> channels-last bf16 ----------
__global__ __launch_bounds__(256) void xpose_kernel(const float* __restrict__ x,
                                                    __bf16* __restrict__ xt) {
    __shared__ float tile[64][33];
    const int bidx = blockIdx.x;            // 4 b * 64 hwt * 4 ct
    const int b   = bidx >> 8;
    const int hw0 = ((bidx >> 2) & 63) * 64;
    const int c0  = (bidx & 3) * 32;
    const int tid = threadIdx.x;
    #pragma unroll
    for (int r = 0; r < 8; ++r) {
        int c_l  = (tid >> 6) + r * 4;
        int hw_l = tid & 63;
        tile[hw_l][c_l] = x[((size_t)(b * CIN + c0 + c_l) << 12) + hw0 + hw_l];
    }
    __syncthreads();
    #pragma unroll
    for (int r = 0; r < 8; ++r) {
        int hw_l = (tid >> 5) + r * 8;
        int c_l  = tid & 31;
        xt[((size_t)(b * 4096 + hw0 + hw_l)) * CIN + c0 + c_l] = (__bf16)tile[hw_l][c_l];
    }
}

// ---------- weight -> A-fragment layout ----------
// wfrag[((ot*36+ks)*64 + lane)*8 + e] = (bf16) w[o*1152 + c*9 + tap]
//   o = ot*16 + (lane&15), k = ks*32 + (lane>>4)*8 + e, tap = k>>7, c = k&127
__global__ __launch_bounds__(256) void wfrag_kernel(const float* __restrict__ w,
                                                    __bf16* __restrict__ wfrag) {
    int t = blockIdx.x * 256 + threadIdx.x;     // [0, 8*36*64)
    if (t >= 8 * KSTEPS * 64) return;
    int lane = t & 63;
    int ks   = (t >> 6) % KSTEPS;
    int ot   = t / (KSTEPS * 64);
    int o    = ot * 16 + (lane & 15);
    v8bf16 frag;
    #pragma unroll
    for (int e = 0; e < 8; ++e) {
        int k   = ks * 32 + (lane >> 4) * 8 + e;
        int tap = k >> 7, c = k & 127;
        frag[e] = (__bf16)w[(size_t)o * KTOT + c * NPT + tap];
    }
    *(v8bf16*)(wfrag + (size_t)t * 8) = frag;
}

__global__ __launch_bounds__(512, 8) void deform_mfma_kernel(
    const float* __restrict__ x, const float* __restrict__ off,
    const float* __restrict__ w, const __bf16* __restrict__ wfrag,
    const __bf16* __restrict__ xt, float* __restrict__ out, int mode)
{
    __shared__ __align__(16) __bf16 Bt[PX][LDBc];         // 25088 B
    __shared__ __align__(8)  unsigned short sIdxP[NDESC][4];
    __shared__ __align__(8)  _Float16      sGP[NDESC][4];

    const int bidx = blockIdx.x;          // 1024 = b(4) * i(64) * jh(2) * oh(2)
    const int b   = bidx >> 8;
    const int i   = (bidx >> 2) & 63;
    const int j0  = ((bidx >> 1) & 1) * PX;
    const int oh  = bidx & 1;
    const int tid = threadIdx.x;

    // ---- Phase S: sampling geometry (d = tap*32 + p) ----
    if (tid < NDESC) {
        int k = tid >> 5, p = tid & 31;
        int j = j0 + p;
        float ox = off[(((b * 18) + 2 * k) * 64 + i) * 64 + j];
        float oy = off[(((b * 18) + 2 * k + 1) * 64 + i) * 64 + j];
        float px = (float)(i + k / 3) + ox;
        float py = (float)(j + k % 3) + oy;
        float fx = floorf(px), fy = floorf(py);
        int qltx = (int)fminf(fmaxf(fx, 0.f), 65.f);
        int qlty = (int)fminf(fmaxf(fy, 0.f), 65.f);
        int qrbx = (int)fminf(fmaxf(fx + 1.f, 0.f), 65.f);
        int qrby = (int)fminf(fmaxf(fy + 1.f, 0.f), 65.f);
        if (px < 1.f || px > 64.f) px = fx;
        if (py < 1.f || py > 64.f) py = fy;
        px = fminf(fmaxf(px, 0.f), 65.f);
        py = fminf(fmaxf(py, 0.f), 65.f);
        float wxl = 1.f + (float)qltx - px;
        float wxr = 1.f - ((float)qrbx - px);
        float wyl = 1.f + (float)qlty - py;
        float wyr = 1.f - ((float)qrby - py);
        float g[4] = { wxl * wyl, wxr * wyr, wxl * wyr, wxr * wyl };
        int qx[4] = { qltx, qrbx, qltx, qrbx };
        int qy[4] = { qlty, qrby, qrby, qlty };
        #pragma unroll
        for (int cr = 0; cr < 4; ++cr) {
            bool inb = (qx[cr] >= 1) && (qx[cr] <= 64) && (qy[cr] >= 1) && (qy[cr] <= 64);
            sIdxP[tid][cr] = inb ? (unsigned short)((qx[cr] - 1) * 64 + (qy[cr] - 1)) : 0;
            sGP[tid][cr]   = inb ? (_Float16)g[cr] : (_Float16)0.f;
        }
    }
    __syncthreads();

    const int l    = tid & 63;
    const int wv   = tid >> 6;        // 0..7
    const int ot   = oh * 4 + (wv & 3);  // 16-o tile index [0,8)
    const int ph   = wv >> 2;            // px half
    const int quad = l >> 4;
    const int lr   = l & 15;

    f32x4 acc = {0.f, 0.f, 0.f, 0.f};

    const __bf16* xtb = xt + ((size_t)b * 4096) * CIN;
    const float*  xb  = x + ((size_t)b * CIN << 12);
    const __bf16* brow = &Bt[ph * 16 + lr][quad * 8];

    for (int t = 0; t < 3; ++t) {
        // ---- stage chunk t: taps 3t..3t+2 (96 desc), 12 per wave ----
        if (mode == 2) {
            #pragma unroll 4
            for (int dd = 0; dd < KSC; ++dd) {
                int dl = wv * KSC + dd;              // [0,96)
                int tap_l = dl >> 5, p = dl & 31;
                int d = t * 96 + dl;
                ushort4v id = *(const ushort4v*)&sIdxP[d][0];
                half4v   gh = *(const half4v*)&sGP[d][0];
                float s0 = 0.f, s1 = 0.f;
                #pragma unroll
                for (int cr = 0; cr < 4; ++cr) {
                    unsigned int v = *(const unsigned int*)(xtb + (size_t)id[cr] * CIN + 2 * l);
                    float c0v, c1v;
                    unsigned int lo = v << 16, hi = v & 0xffff0000u;
                    __builtin_memcpy(&c0v, &lo, 4);
                    __builtin_memcpy(&c1v, &hi, 4);
                    float gf = (float)gh[cr];
                    s0 += gf * c0v;
                    s1 += gf * c1v;
                }
                bf16x2 pr = { (__bf16)s0, (__bf16)s1 };
                *(bf16x2*)&Bt[p][tap_l * CIN + 2 * l] = pr;
            }
        } else {
            for (int dd = 0; dd < KSC; ++dd) {
                int dl = wv * KSC + dd;
                int tap_l = dl >> 5, p = dl & 31;
                int d = t * 96 + dl;
                ushort4v id = *(const ushort4v*)&sIdxP[d][0];
                half4v   gh = *(const half4v*)&sGP[d][0];
                float s0 = 0.f, s1 = 0.f;
                #pragma unroll
                for (int cr = 0; cr < 4; ++cr) {
                    float gf = (float)gh[cr];
                    s0 += gf * xb[((size_t)(2 * l) << 12) + id[cr]];
                    s1 += gf * xb[((size_t)(2 * l + 1) << 12) + id[cr]];
                }
                bf16x2 pr = { (__bf16)s0, (__bf16)s1 };
                *(bf16x2*)&Bt[p][tap_l * CIN + 2 * l] = pr;
            }
        }
        __syncthreads();

        // ---- MFMA: 12 K-steps, one afrag + one bfrag per step ----
        #pragma unroll 4
        for (int ks = 0; ks < KSC; ++ks) {
            int ks_g = t * KSC + ks;
            v8bf16 bfrag = *(const v8bf16*)(brow + ks * 32);
            v8bf16 afrag;
            if (mode >= 1) {
                afrag = *(const v8bf16*)(wfrag + (((size_t)ot * KSTEPS + ks_g) * 64 + l) * 8);
            } else {
                int o = ot * 16 + lr;
                #pragma unroll
                for (int e = 0; e < 8; ++e) {
                    int k = ks_g * 32 + quad * 8 + e;
                    int tap = k >> 7, c = k & 127;
                    afrag[e] = (__bf16)w[(size_t)o * KTOT + c * NPT + tap];
                }
            }
            acc = __builtin_amdgcn_mfma_f32_16x16x32_bf16(afrag, bfrag, acc, 0, 0, 0);
        }
        if (t < 2) __syncthreads();
    }

    // ---- epilogue: o = ot*16 + quad*4 + r, col j = j0 + ph*16 + lr ----
    {
        int obase = ot * 16 + quad * 4;
        float* op = out + (((size_t)(b * OC + obase)) << 12) + (i << 6) + j0 + ph * 16 + lr;
        #pragma unroll
        for (int r = 0; r < 4; ++r)
            op[(size_t)r << 12] = acc[r];
    }
}

extern "C" void kernel_launch(void* const* d_in, const int* in_sizes, int n_in,
                              void* d_out, int out_size, void* d_ws, size_t ws_size,
                              hipStream_t stream) {
    const float* x   = (const float*)d_in[0];
    const float* off = (const float*)d_in[1];
    const float* w   = (const float*)d_in[2];
    float* out = (float*)d_out;

    const size_t wfrag_bytes = (size_t)OC * KTOT * sizeof(__bf16);      // 294912
    const size_t xt_bytes    = (size_t)4 * 4096 * CIN * sizeof(__bf16); // 4 MB
    int mode = 0;
    if (ws_size >= wfrag_bytes + xt_bytes) mode = 2;
    else if (ws_size >= wfrag_bytes) mode = 1;

    __bf16* wfrag = (__bf16*)d_ws;
    __bf16* xt    = (__bf16*)((char*)d_ws + wfrag_bytes);

    if (mode >= 1) {
        wfrag_kernel<<<(8 * KSTEPS * 64 + 255) / 256, 256, 0, stream>>>(w, wfrag);
    }
    if (mode == 2) {
        xpose_kernel<<<4 * 64 * 4, 256, 0, stream>>>(x, xt);
    }
    deform_mfma_kernel<<<4 * 64 * 2 * 2, 512, 0, stream>>>(x, off, w, wfrag, xt, out, mode);
}

// Round 6
// 106.914 us; speedup vs baseline: 1.0386x; 1.0386x over previous
//
#include <hip/hip_runtime.h>

// DeformConv2D b=4,c=128,H=W=64,outc=128,KS=3,PAD=1,N=9
// Split pipeline (mode 3):
//   1) xpose : x NCHW fp32 -> xt (b,hw,c) bf16
//   2) wfrag : weight -> MFMA A-frag layout [ot][ks][lane][8]
//   3) desck : 147456 sample descriptors (idx4 u16 + g4 f16, 16B each)
//   4) sample: 1 wave/descriptor -> Bmat[(b*4096+hw)*1152 + tap*128 + c] bf16
//   5) gemm  : C[16384,128] = Bmat[16384,1152] x W^T, 32px x 128o blocks
// Fallback (mode<=2): round-4 fused kernel (verified).

typedef __bf16  v8bf16 __attribute__((ext_vector_type(8)));
typedef __bf16  bf16x2 __attribute__((ext_vector_type(2)));
typedef float   f32x4  __attribute__((ext_vector_type(4)));
typedef unsigned short ushort4v __attribute__((ext_vector_type(4)));
typedef _Float16 half4v __attribute__((ext_vector_type(4)));

#define CIN  128
#define NPT  9
#define KTOT 1152
#define OC   128
#define PX   32
#define NDESC (NPT * PX)
#define KSTEPS 36
#define KSC  12
#define LDBc 392
#define DTOT (9 * 4 * 64 * 64)   // 147456 descriptors

// ---------- x NCHW fp32 -> channels-last bf16 ----------
__global__ __launch_bounds__(256) void xpose_kernel(const float* __restrict__ x,
                                                    __bf16* __restrict__ xt) {
    __shared__ float tile[64][33];
    const int bidx = blockIdx.x;
    const int b   = bidx >> 8;
    const int hw0 = ((bidx >> 2) & 63) * 64;
    const int c0  = (bidx & 3) * 32;
    const int tid = threadIdx.x;
    #pragma unroll
    for (int r = 0; r < 8; ++r) {
        int c_l  = (tid >> 6) + r * 4;
        int hw_l = tid & 63;
        tile[hw_l][c_l] = x[((size_t)(b * CIN + c0 + c_l) << 12) + hw0 + hw_l];
    }
    __syncthreads();
    #pragma unroll
    for (int r = 0; r < 8; ++r) {
        int hw_l = (tid >> 5) + r * 8;
        int c_l  = tid & 31;
        xt[((size_t)(b * 4096 + hw0 + hw_l)) * CIN + c0 + c_l] = (__bf16)tile[hw_l][c_l];
    }
}

// ---------- weight -> A-fragment layout ----------
__global__ __launch_bounds__(256) void wfrag_kernel(const float* __restrict__ w,
                                                    __bf16* __restrict__ wfrag) {
    int t = blockIdx.x * 256 + threadIdx.x;
    if (t >= 8 * KSTEPS * 64) return;
    int lane = t & 63;
    int ks   = (t >> 6) % KSTEPS;
    int ot   = t / (KSTEPS * 64);
    int o    = ot * 16 + (lane & 15);
    v8bf16 frag;
    #pragma unroll
    for (int e = 0; e < 8; ++e) {
        int k   = ks * 32 + (lane >> 4) * 8 + e;
        int tap = k >> 7, c = k & 127;
        frag[e] = (__bf16)w[(size_t)o * KTOT + c * NPT + tap];
    }
    *(v8bf16*)(wfrag + (size_t)t * 8) = frag;
}

// ---------- descriptor kernel: one thread per (tap,b,i,j) ----------
__global__ __launch_bounds__(256) void desc_kernel(const float* __restrict__ off,
                                                   uint4* __restrict__ desc) {
    int t = blockIdx.x * 256 + threadIdx.x;
    if (t >= DTOT) return;
    int j   = t & 63;
    int i   = (t >> 6) & 63;
    int b   = (t >> 12) & 3;
    int tap = t >> 14;

    float ox = off[(((b * 18) + 2 * tap) << 12) + (i << 6) + j];
    float oy = off[(((b * 18) + 2 * tap + 1) << 12) + (i << 6) + j];
    float px = (float)(i + tap / 3) + ox;
    float py = (float)(j + tap % 3) + oy;
    float fx = floorf(px), fy = floorf(py);
    int qltx = (int)fminf(fmaxf(fx, 0.f), 65.f);
    int qlty = (int)fminf(fmaxf(fy, 0.f), 65.f);
    int qrbx = (int)fminf(fmaxf(fx + 1.f, 0.f), 65.f);
    int qrby = (int)fminf(fmaxf(fy + 1.f, 0.f), 65.f);
    if (px < 1.f || px > 64.f) px = fx;
    if (py < 1.f || py > 64.f) py = fy;
    px = fminf(fmaxf(px, 0.f), 65.f);
    py = fminf(fmaxf(py, 0.f), 65.f);
    float wxl = 1.f + (float)qltx - px;
    float wxr = 1.f - ((float)qrbx - px);
    float wyl = 1.f + (float)qlty - py;
    float wyr = 1.f - ((float)qrby - py);
    float g[4] = { wxl * wyl, wxr * wyr, wxl * wyr, wxr * wyl };
    int qx[4] = { qltx, qrbx, qltx, qrbx };
    int qy[4] = { qlty, qrby, qrby, qlty };
    unsigned short idx[4];
    half4v gh;
    #pragma unroll
    for (int cr = 0; cr < 4; ++cr) {
        bool inb = (qx[cr] >= 1) && (qx[cr] <= 64) && (qy[cr] >= 1) && (qy[cr] <= 64);
        idx[cr] = inb ? (unsigned short)((qx[cr] - 1) * 64 + (qy[cr] - 1)) : 0;
        gh[cr]  = inb ? (_Float16)g[cr] : (_Float16)0.f;
    }
    uint4 rec;
    rec.x = (unsigned)idx[0] | ((unsigned)idx[1] << 16);
    rec.y = (unsigned)idx[2] | ((unsigned)idx[3] << 16);
    __builtin_memcpy(&rec.z, &gh, 8);
    int d = (((b << 6) + i) * 64 + j) * 9 + tap;
    desc[d] = rec;
}

// ---------- sampling kernel: one wave per descriptor, 32 descs per wave ----------
__global__ __launch_bounds__(256, 8) void sample_kernel(const uint4* __restrict__ desc,
                                                        const __bf16* __restrict__ xt,
                                                        __bf16* __restrict__ bmat) {
    const int wave = blockIdx.x * 4 + (threadIdx.x >> 6);   // [0, 4608)
    const int l    = threadIdx.x & 63;
    const int base = wave * 32;
    const int b    = wave / 1152;                            // 36864 descs per b
    const __bf16* xtb = xt + ((size_t)b << 12) * CIN;

    #pragma unroll 4
    for (int it = 0; it < 32; ++it) {
        int d = base + it;
        uint4 q = desc[d];
        unsigned short i0 = q.x & 0xffff, i1 = q.x >> 16;
        unsigned short i2 = q.y & 0xffff, i3 = q.y >> 16;
        half4v gh;
        __builtin_memcpy(&gh, &q.z, 8);
        unsigned short idx[4] = { i0, i1, i2, i3 };
        float s0 = 0.f, s1 = 0.f;
        #pragma unroll
        for (int cr = 0; cr < 4; ++cr) {
            unsigned int v = *(const unsigned int*)(xtb + (size_t)idx[cr] * CIN + 2 * l);
            float c0v, c1v;
            unsigned int lo = v << 16, hi = v & 0xffff0000u;
            __builtin_memcpy(&c0v, &lo, 4);
            __builtin_memcpy(&c1v, &hi, 4);
            float gf = (float)gh[cr];
            s0 += gf * c0v;
            s1 += gf * c1v;
        }
        int rowpx = d / 9;
        int tap   = d - rowpx * 9;
        bf16x2 pr = { (__bf16)s0, (__bf16)s1 };
        *(bf16x2*)(bmat + (size_t)rowpx * KTOT + tap * CIN + 2 * l) = pr;
    }
}

// ---------- GEMM kernel: 32px x 128o per block ----------
__global__ __launch_bounds__(512, 8) void gemm_kernel(const __bf16* __restrict__ bmat,
                                                      const __bf16* __restrict__ wfrag,
                                                      float* __restrict__ out) {
    __shared__ __align__(16) __bf16 Bt[PX][LDBc];   // 25088 B

    const int bidx = blockIdx.x;      // 512 = b(4) * i(64) * jh(2)
    const int b   = bidx >> 7;
    const int i   = (bidx >> 1) & 63;
    const int j0  = (bidx & 1) * PX;
    const int tid = threadIdx.x;

    const int l    = tid & 63;
    const int wv   = tid >> 6;        // 0..7
    const int otp  = wv & 3;          // o-tile pair: ot = otp*2 + mt
    const int ph   = wv >> 2;         // px half
    const int quad = l >> 4;
    const int lr   = l & 15;

    const size_t row_base = ((size_t)b << 12) + (i << 6) + j0;
    const int r_st = tid >> 4;        // staging row [0,32)
    const int s_st = tid & 15;        // staging seg

    f32x4 acc0 = {0.f, 0.f, 0.f, 0.f};
    f32x4 acc1 = {0.f, 0.f, 0.f, 0.f};
    const __bf16* brow = &Bt[ph * 16 + lr][quad * 8];

    for (int t = 0; t < 3; ++t) {
        // stage 32 rows x 384 k (768 B/row) with plain b128 copies
        const __bf16* gsrc = bmat + (row_base + r_st) * KTOT + t * 384;
        #pragma unroll
        for (int it = 0; it < 3; ++it) {
            int seg = it * 16 + s_st;     // [0,48)
            *(v8bf16*)&Bt[r_st][seg * 8] = *(const v8bf16*)(gsrc + seg * 8);
        }
        __syncthreads();

        #pragma unroll 4
        for (int ks = 0; ks < KSC; ++ks) {
            int ks_g = t * KSC + ks;
            v8bf16 bfrag = *(const v8bf16*)(brow + ks * 32);
            v8bf16 a0 = *(const v8bf16*)(wfrag + (((size_t)(otp * 2) * KSTEPS + ks_g) * 64 + l) * 8);
            v8bf16 a1 = *(const v8bf16*)(wfrag + (((size_t)(otp * 2 + 1) * KSTEPS + ks_g) * 64 + l) * 8);
            acc0 = __builtin_amdgcn_mfma_f32_16x16x32_bf16(a0, bfrag, acc0, 0, 0, 0);
            acc1 = __builtin_amdgcn_mfma_f32_16x16x32_bf16(a1, bfrag, acc1, 0, 0, 0);
        }
        if (t < 2) __syncthreads();
    }

    #pragma unroll
    for (int mt = 0; mt < 2; ++mt) {
        int obase = (otp * 2 + mt) * 16 + quad * 4;
        float* op = out + (((size_t)(b * OC + obase)) << 12) + (i << 6) + j0 + ph * 16 + lr;
        f32x4 a = (mt == 0) ? acc0 : acc1;
        #pragma unroll
        for (int r = 0; r < 4; ++r)
            op[(size_t)r << 12] = a[r];
    }
}

// ---------- round-4 fused fallback (verified) ----------
__global__ __launch_bounds__(512, 8) void deform_fused_kernel(
    const float* __restrict__ x, const float* __restrict__ off,
    const float* __restrict__ w, const __bf16* __restrict__ wfrag,
    const __bf16* __restrict__ xt, float* __restrict__ out, int mode)
{
    __shared__ __align__(16) __bf16 Bt[PX][LDBc];
    __shared__ __align__(8)  unsigned short sIdxP[NDESC][4];
    __shared__ __align__(8)  _Float16      sGP[NDESC][4];

    const int bidx = blockIdx.x;
    const int b   = bidx >> 8;
    const int i   = (bidx >> 2) & 63;
    const int j0  = ((bidx >> 1) & 1) * PX;
    const int oh  = bidx & 1;
    const int tid = threadIdx.x;

    if (tid < NDESC) {
        int k = tid >> 5, p = tid & 31;
        int j = j0 + p;
        float ox = off[(((b * 18) + 2 * k) * 64 + i) * 64 + j];
        float oy = off[(((b * 18) + 2 * k + 1) * 64 + i) * 64 + j];
        float px = (float)(i + k / 3) + ox;
        float py = (float)(j + k % 3) + oy;
        float fx = floorf(px), fy = floorf(py);
        int qltx = (int)fminf(fmaxf(fx, 0.f), 65.f);
        int qlty = (int)fminf(fmaxf(fy, 0.f), 65.f);
        int qrbx = (int)fminf(fmaxf(fx + 1.f, 0.f), 65.f);
        int qrby = (int)fminf(fmaxf(fy + 1.f, 0.f), 65.f);
        if (px < 1.f || px > 64.f) px = fx;
        if (py < 1.f || py > 64.f) py = fy;
        px = fminf(fmaxf(px, 0.f), 65.f);
        py = fminf(fmaxf(py, 0.f), 65.f);
        float wxl = 1.f + (float)qltx - px;
        float wxr = 1.f - ((float)qrbx - px);
        float wyl = 1.f + (float)qlty - py;
        float wyr = 1.f - ((float)qrby - py);
        float g[4] = { wxl * wyl, wxr * wyr, wxl * wyr, wxr * wyl };
        int qx[4] = { qltx, qrbx, qltx, qrbx };
        int qy[4] = { qlty, qrby, qrby, qlty };
        #pragma unroll
        for (int cr = 0; cr < 4; ++cr) {
            bool inb = (qx[cr] >= 1) && (qx[cr] <= 64) && (qy[cr] >= 1) && (qy[cr] <= 64);
            sIdxP[tid][cr] = inb ? (unsigned short)((qx[cr] - 1) * 64 + (qy[cr] - 1)) : 0;
            sGP[tid][cr]   = inb ? (_Float16)g[cr] : (_Float16)0.f;
        }
    }
    __syncthreads();

    const int l    = tid & 63;
    const int wv   = tid >> 6;
    const int ot   = oh * 4 + (wv & 3);
    const int ph   = wv >> 2;
    const int quad = l >> 4;
    const int lr   = l & 15;

    f32x4 acc = {0.f, 0.f, 0.f, 0.f};
    const __bf16* xtb = xt + ((size_t)b * 4096) * CIN;
    const float*  xb  = x + ((size_t)b * CIN << 12);
    const __bf16* brow = &Bt[ph * 16 + lr][quad * 8];

    for (int t = 0; t < 3; ++t) {
        if (mode == 2) {
            #pragma unroll 4
            for (int dd = 0; dd < KSC; ++dd) {
                int dl = wv * KSC + dd;
                int tap_l = dl >> 5, p = dl & 31;
                int d = t * 96 + dl;
                ushort4v id = *(const ushort4v*)&sIdxP[d][0];
                half4v   gh = *(const half4v*)&sGP[d][0];
                float s0 = 0.f, s1 = 0.f;
                #pragma unroll
                for (int cr = 0; cr < 4; ++cr) {
                    unsigned int v = *(const unsigned int*)(xtb + (size_t)id[cr] * CIN + 2 * l);
                    float c0v, c1v;
                    unsigned int lo = v << 16, hi = v & 0xffff0000u;
                    __builtin_memcpy(&c0v, &lo, 4);
                    __builtin_memcpy(&c1v, &hi, 4);
                    float gf = (float)gh[cr];
                    s0 += gf * c0v;
                    s1 += gf * c1v;
                }
                bf16x2 pr = { (__bf16)s0, (__bf16)s1 };
                *(bf16x2*)&Bt[p][tap_l * CIN + 2 * l] = pr;
            }
        } else {
            for (int dd = 0; dd < KSC; ++dd) {
                int dl = wv * KSC + dd;
                int tap_l = dl >> 5, p = dl & 31;
                int d = t * 96 + dl;
                ushort4v id = *(const ushort4v*)&sIdxP[d][0];
                half4v   gh = *(const half4v*)&sGP[d][0];
                float s0 = 0.f, s1 = 0.f;
                #pragma unroll
                for (int cr = 0; cr < 4; ++cr) {
                    float gf = (float)gh[cr];
                    s0 += gf * xb[((size_t)(2 * l) << 12) + id[cr]];
                    s1 += gf * xb[((size_t)(2 * l + 1) << 12) + id[cr]];
                }
                bf16x2 pr = { (__bf16)s0, (__bf16)s1 };
                *(bf16x2*)&Bt[p][tap_l * CIN + 2 * l] = pr;
            }
        }
        __syncthreads();

        #pragma unroll 4
        for (int ks = 0; ks < KSC; ++ks) {
            int ks_g = t * KSC + ks;
            v8bf16 bfrag = *(const v8bf16*)(brow + ks * 32);
            v8bf16 afrag;
            if (mode >= 1) {
                afrag = *(const v8bf16*)(wfrag + (((size_t)ot * KSTEPS + ks_g) * 64 + l) * 8);
            } else {
                int o = ot * 16 + lr;
                #pragma unroll
                for (int e = 0; e < 8; ++e) {
                    int k = ks_g * 32 + quad * 8 + e;
                    int tap = k >> 7, c = k & 127;
                    afrag[e] = (__bf16)w[(size_t)o * KTOT + c * NPT + tap];
                }
            }
            acc = __builtin_amdgcn_mfma_f32_16x16x32_bf16(afrag, bfrag, acc, 0, 0, 0);
        }
        if (t < 2) __syncthreads();
    }

    {
        int obase = ot * 16 + quad * 4;
        float* op = out + (((size_t)(b * OC + obase)) << 12) + (i << 6) + j0 + ph * 16 + lr;
        #pragma unroll
        for (int r = 0; r < 4; ++r)
            op[(size_t)r << 12] = acc[r];
    }
}

extern "C" void kernel_launch(void* const* d_in, const int* in_sizes, int n_in,
                              void* d_out, int out_size, void* d_ws, size_t ws_size,
                              hipStream_t stream) {
    const float* x   = (const float*)d_in[0];
    const float* off = (const float*)d_in[1];
    const float* w   = (const float*)d_in[2];
    float* out = (float*)d_out;

    const size_t wfrag_bytes = (size_t)OC * KTOT * sizeof(__bf16);        // 294912
    const size_t xt_bytes    = (size_t)4 * 4096 * CIN * sizeof(__bf16);   // 4 MB
    const size_t desc_bytes  = (size_t)DTOT * 16;                         // 2.36 MB
    const size_t bmat_bytes  = (size_t)4 * 4096 * KTOT * sizeof(__bf16);  // 37.75 MB

    int mode = 0;
    if (ws_size >= wfrag_bytes + xt_bytes + desc_bytes + bmat_bytes) mode = 3;
    else if (ws_size >= wfrag_bytes + xt_bytes) mode = 2;
    else if (ws_size >= wfrag_bytes) mode = 1;

    __bf16* wfrag = (__bf16*)d_ws;
    __bf16* xt    = (__bf16*)((char*)d_ws + wfrag_bytes);
    uint4*  desc  = (uint4*) ((char*)d_ws + wfrag_bytes + xt_bytes);
    __bf16* bmat  = (__bf16*)((char*)d_ws + wfrag_bytes + xt_bytes + desc_bytes);

    if (mode >= 1)
        wfrag_kernel<<<(8 * KSTEPS * 64 + 255) / 256, 256, 0, stream>>>(w, wfrag);
    if (mode >= 2)
        xpose_kernel<<<4 * 64 * 4, 256, 0, stream>>>(x, xt);

    if (mode == 3) {
        desc_kernel<<<(DTOT + 255) / 256, 256, 0, stream>>>(off, desc);
        sample_kernel<<<1152, 256, 0, stream>>>(desc, xt, bmat);
        gemm_kernel<<<512, 512, 0, stream>>>(bmat, wfrag, out);
    } else {
        deform_fused_kernel<<<4 * 64 * 2 * 2, 512, 0, stream>>>(x, off, w, wfrag, xt, out, mode);
    }
}

// Round 7
// 105.742 us; speedup vs baseline: 1.0501x; 1.0111x over previous
//
#include <hip/hip_runtime.h>

// DeformConv2D b=4,c=128,H=W=64,outc=128,KS=3,PAD=1,N=9
// Split-K fused pipeline (mode 3):
//   1) xpose : x NCHW fp32 -> xt (b,hw,c) bf16
//   2) wfrag : weight -> MFMA A-frag layout [ot][ks][lane][8]
//   3) desck : 147456 sample descriptors (idx4 u16 + g4 f16, 16B each)
//   4) splitk: grid 1024 = b4*i64*jh2*kh2. kh0: taps 0-4, kh1: taps 5-8.
//              stage tap-subset bilinear -> LDS, MFMA, fp32 partials -> ws
//   5) reduce: out = part0 + part1
// Fallback (mode<=2): round-5 fused kernel (verified).

typedef __bf16  v8bf16 __attribute__((ext_vector_type(8)));
typedef __bf16  bf16x2 __attribute__((ext_vector_type(2)));
typedef float   f32x4  __attribute__((ext_vector_type(4)));
typedef unsigned short ushort4v __attribute__((ext_vector_type(4)));
typedef _Float16 half4v __attribute__((ext_vector_type(4)));

#define CIN  128
#define NPT  9
#define KTOT 1152
#define OC   128
#define PX   32
#define NDESC (NPT * PX)
#define KSTEPS 36
#define KSC  12
#define LDBc 392
#define DTOT (9 * 4 * 64 * 64)   // 147456
#define LDH  648                 // splitk Bt row stride (bf16): 5*128+8

// ---------- x NCHW fp32 -> channels-last bf16 ----------
__global__ __launch_bounds__(256) void xpose_kernel(const float* __restrict__ x,
                                                    __bf16* __restrict__ xt) {
    __shared__ float tile[64][33];
    const int bidx = blockIdx.x;
    const int b   = bidx >> 8;
    const int hw0 = ((bidx >> 2) & 63) * 64;
    const int c0  = (bidx & 3) * 32;
    const int tid = threadIdx.x;
    #pragma unroll
    for (int r = 0; r < 8; ++r) {
        int c_l  = (tid >> 6) + r * 4;
        int hw_l = tid & 63;
        tile[hw_l][c_l] = x[((size_t)(b * CIN + c0 + c_l) << 12) + hw0 + hw_l];
    }
    __syncthreads();
    #pragma unroll
    for (int r = 0; r < 8; ++r) {
        int hw_l = (tid >> 5) + r * 8;
        int c_l  = tid & 31;
        xt[((size_t)(b * 4096 + hw0 + hw_l)) * CIN + c0 + c_l] = (__bf16)tile[hw_l][c_l];
    }
}

// ---------- weight -> A-fragment layout ----------
__global__ __launch_bounds__(256) void wfrag_kernel(const float* __restrict__ w,
                                                    __bf16* __restrict__ wfrag) {
    int t = blockIdx.x * 256 + threadIdx.x;
    if (t >= 8 * KSTEPS * 64) return;
    int lane = t & 63;
    int ks   = (t >> 6) % KSTEPS;
    int ot   = t / (KSTEPS * 64);
    int o    = ot * 16 + (lane & 15);
    v8bf16 frag;
    #pragma unroll
    for (int e = 0; e < 8; ++e) {
        int k   = ks * 32 + (lane >> 4) * 8 + e;
        int tap = k >> 7, c = k & 127;
        frag[e] = (__bf16)w[(size_t)o * KTOT + c * NPT + tap];
    }
    *(v8bf16*)(wfrag + (size_t)t * 8) = frag;
}

// ---------- descriptor kernel: one thread per (tap,b,i,j) ----------
__global__ __launch_bounds__(256) void desc_kernel(const float* __restrict__ off,
                                                   uint4* __restrict__ desc) {
    int t = blockIdx.x * 256 + threadIdx.x;
    if (t >= DTOT) return;
    int j   = t & 63;
    int i   = (t >> 6) & 63;
    int b   = (t >> 12) & 3;
    int tap = t >> 14;

    float ox = off[(((b * 18) + 2 * tap) << 12) + (i << 6) + j];
    float oy = off[(((b * 18) + 2 * tap + 1) << 12) + (i << 6) + j];
    float px = (float)(i + tap / 3) + ox;
    float py = (float)(j + tap % 3) + oy;
    float fx = floorf(px), fy = floorf(py);
    int qltx = (int)fminf(fmaxf(fx, 0.f), 65.f);
    int qlty = (int)fminf(fmaxf(fy, 0.f), 65.f);
    int qrbx = (int)fminf(fmaxf(fx + 1.f, 0.f), 65.f);
    int qrby = (int)fminf(fmaxf(fy + 1.f, 0.f), 65.f);
    if (px < 1.f || px > 64.f) px = fx;
    if (py < 1.f || py > 64.f) py = fy;
    px = fminf(fmaxf(px, 0.f), 65.f);
    py = fminf(fmaxf(py, 0.f), 65.f);
    float wxl = 1.f + (float)qltx - px;
    float wxr = 1.f - ((float)qrbx - px);
    float wyl = 1.f + (float)qlty - py;
    float wyr = 1.f - ((float)qrby - py);
    float g[4] = { wxl * wyl, wxr * wyr, wxl * wyr, wxr * wyl };
    int qx[4] = { qltx, qrbx, qltx, qrbx };
    int qy[4] = { qlty, qrby, qrby, qlty };
    unsigned short idx[4];
    half4v gh;
    #pragma unroll
    for (int cr = 0; cr < 4; ++cr) {
        bool inb = (qx[cr] >= 1) && (qx[cr] <= 64) && (qy[cr] >= 1) && (qy[cr] <= 64);
        idx[cr] = inb ? (unsigned short)((qx[cr] - 1) * 64 + (qy[cr] - 1)) : 0;
        gh[cr]  = inb ? (_Float16)g[cr] : (_Float16)0.f;
    }
    uint4 rec;
    rec.x = (unsigned)idx[0] | ((unsigned)idx[1] << 16);
    rec.y = (unsigned)idx[2] | ((unsigned)idx[3] << 16);
    __builtin_memcpy(&rec.z, &gh, 8);
    int d = (((b << 6) + i) * 64 + j) * 9 + tap;
    desc[d] = rec;
}

// ---------- split-K fused kernel ----------
__global__ __launch_bounds__(512, 6) void splitk_kernel(
    const uint4* __restrict__ desc, const __bf16* __restrict__ xt,
    const __bf16* __restrict__ wfrag, float* __restrict__ part)
{
    __shared__ __align__(16) __bf16 Bt[PX][LDH];   // 41472 B

    const int bidx = blockIdx.x;     // 1024 = b(4) * i(64) * jh(2) * kh(2)
    const int kh  = bidx & 1;
    const int j0  = ((bidx >> 1) & 1) * PX;
    const int i   = (bidx >> 2) & 63;
    const int b   = bidx >> 8;
    const int tid = threadIdx.x;

    const int tap0    = kh ? 5 : 0;
    const int ntap    = kh ? 4 : 5;
    const int ndesc_h = ntap * 32;      // 128 or 160
    const int nks     = ntap * 4;       // 16 or 20

    const int l  = tid & 63;
    const int wv = tid >> 6;            // 0..7

    const __bf16* xtb = xt + (((size_t)b << 12) * CIN);
    const int pix_base = ((b << 6) + i) * 64 + j0;

    // ---- stage: bilinear samples for taps [tap0, tap0+ntap) ----
    for (int dl = wv; dl < ndesc_h; dl += 8) {
        int tap_l = dl >> 5, p = dl & 31;
        int d = (pix_base + p) * 9 + tap0 + tap_l;
        uint4 q = desc[d];
        unsigned short idx[4] = { (unsigned short)(q.x & 0xffff), (unsigned short)(q.x >> 16),
                                  (unsigned short)(q.y & 0xffff), (unsigned short)(q.y >> 16) };
        half4v gh;
        __builtin_memcpy(&gh, &q.z, 8);
        float s0 = 0.f, s1 = 0.f;
        #pragma unroll
        for (int cr = 0; cr < 4; ++cr) {
            unsigned int v = *(const unsigned int*)(xtb + (size_t)idx[cr] * CIN + 2 * l);
            float c0v, c1v;
            unsigned int lo = v << 16, hi = v & 0xffff0000u;
            __builtin_memcpy(&c0v, &lo, 4);
            __builtin_memcpy(&c1v, &hi, 4);
            float gf = (float)gh[cr];
            s0 += gf * c0v;
            s1 += gf * c1v;
        }
        bf16x2 pr = { (__bf16)s0, (__bf16)s1 };
        *(bf16x2*)&Bt[p][tap_l * CIN + 2 * l] = pr;
    }
    __syncthreads();

    // ---- MFMA: wave = ot-pair (wv&3) x px-half (wv>>2) ----
    const int otp  = wv & 3;
    const int ph   = wv >> 2;
    const int quad = l >> 4;
    const int lr   = l & 15;

    f32x4 acc0 = {0.f, 0.f, 0.f, 0.f};
    f32x4 acc1 = {0.f, 0.f, 0.f, 0.f};
    const __bf16* brow = &Bt[ph * 16 + lr][quad * 8];

    #pragma unroll 4
    for (int ks = 0; ks < nks; ++ks) {
        int ks_g = tap0 * 4 + ks;
        v8bf16 bfrag = *(const v8bf16*)(brow + ks * 32);
        v8bf16 a0 = *(const v8bf16*)(wfrag + (((size_t)(otp * 2) * KSTEPS + ks_g) * 64 + l) * 8);
        v8bf16 a1 = *(const v8bf16*)(wfrag + (((size_t)(otp * 2 + 1) * KSTEPS + ks_g) * 64 + l) * 8);
        acc0 = __builtin_amdgcn_mfma_f32_16x16x32_bf16(a0, bfrag, acc0, 0, 0, 0);
        acc1 = __builtin_amdgcn_mfma_f32_16x16x32_bf16(a1, bfrag, acc1, 0, 0, 0);
    }

    // ---- epilogue -> partials[kh] ----
    float* pc = part + ((size_t)kh << 21);   // 2 x 2097152 floats
    #pragma unroll
    for (int mt = 0; mt < 2; ++mt) {
        int obase = (otp * 2 + mt) * 16 + quad * 4;
        float* op = pc + (((size_t)(b * OC + obase)) << 12) + (i << 6) + j0 + ph * 16 + lr;
        f32x4 a = (mt == 0) ? acc0 : acc1;
        #pragma unroll
        for (int r = 0; r < 4; ++r)
            op[(size_t)r << 12] = a[r];
    }
}

// ---------- reduce: out = part0 + part1 ----------
__global__ __launch_bounds__(256) void reduce_kernel(const float* __restrict__ part,
                                                     float* __restrict__ out) {
    int t = blockIdx.x * 256 + threadIdx.x;   // 524288 threads, float4 each
    f32x4 a = *(const f32x4*)(part + (size_t)t * 4);
    f32x4 c = *(const f32x4*)(part + (1u << 21) + (size_t)t * 4);
    f32x4 r = a + c;
    *(f32x4*)(out + (size_t)t * 4) = r;
}

// ---------- round-5 fused fallback (verified) ----------
__global__ __launch_bounds__(512, 8) void deform_fused_kernel(
    const float* __restrict__ x, const float* __restrict__ off,
    const float* __restrict__ w, const __bf16* __restrict__ wfrag,
    const __bf16* __restrict__ xt, float* __restrict__ out, int mode)
{
    __shared__ __align__(16) __bf16 Bt[PX][LDBc];
    __shared__ __align__(8)  unsigned short sIdxP[NDESC][4];
    __shared__ __align__(8)  _Float16      sGP[NDESC][4];

    const int bidx = blockIdx.x;
    const int b   = bidx >> 8;
    const int i   = (bidx >> 2) & 63;
    const int j0  = ((bidx >> 1) & 1) * PX;
    const int oh  = bidx & 1;
    const int tid = threadIdx.x;

    if (tid < NDESC) {
        int k = tid >> 5, p = tid & 31;
        int j = j0 + p;
        float ox = off[(((b * 18) + 2 * k) * 64 + i) * 64 + j];
        float oy = off[(((b * 18) + 2 * k + 1) * 64 + i) * 64 + j];
        float px = (float)(i + k / 3) + ox;
        float py = (float)(j + k % 3) + oy;
        float fx = floorf(px), fy = floorf(py);
        int qltx = (int)fminf(fmaxf(fx, 0.f), 65.f);
        int qlty = (int)fminf(fmaxf(fy, 0.f), 65.f);
        int qrbx = (int)fminf(fmaxf(fx + 1.f, 0.f), 65.f);
        int qrby = (int)fminf(fmaxf(fy + 1.f, 0.f), 65.f);
        if (px < 1.f || px > 64.f) px = fx;
        if (py < 1.f || py > 64.f) py = fy;
        px = fminf(fmaxf(px, 0.f), 65.f);
        py = fminf(fmaxf(py, 0.f), 65.f);
        float wxl = 1.f + (float)qltx - px;
        float wxr = 1.f - ((float)qrbx - px);
        float wyl = 1.f + (float)qlty - py;
        float wyr = 1.f - ((float)qrby - py);
        float g[4] = { wxl * wyl, wxr * wyr, wxl * wyr, wxr * wyl };
        int qx[4] = { qltx, qrbx, qltx, qrbx };
        int qy[4] = { qlty, qrby, qrby, qlty };
        #pragma unroll
        for (int cr = 0; cr < 4; ++cr) {
            bool inb = (qx[cr] >= 1) && (qx[cr] <= 64) && (qy[cr] >= 1) && (qy[cr] <= 64);
            sIdxP[tid][cr] = inb ? (unsigned short)((qx[cr] - 1) * 64 + (qy[cr] - 1)) : 0;
            sGP[tid][cr]   = inb ? (_Float16)g[cr] : (_Float16)0.f;
        }
    }
    __syncthreads();

    const int l    = tid & 63;
    const int wv   = tid >> 6;
    const int ot   = oh * 4 + (wv & 3);
    const int ph   = wv >> 2;
    const int quad = l >> 4;
    const int lr   = l & 15;

    f32x4 acc = {0.f, 0.f, 0.f, 0.f};
    const __bf16* xtb = xt + ((size_t)b * 4096) * CIN;
    const float*  xb  = x + ((size_t)b * CIN << 12);
    const __bf16* brow = &Bt[ph * 16 + lr][quad * 8];

    for (int t = 0; t < 3; ++t) {
        if (mode == 2) {
            #pragma unroll 4
            for (int dd = 0; dd < KSC; ++dd) {
                int dl = wv * KSC + dd;
                int tap_l = dl >> 5, p = dl & 31;
                int d = t * 96 + dl;
                ushort4v id = *(const ushort4v*)&sIdxP[d][0];
                half4v   gh = *(const half4v*)&sGP[d][0];
                float s0 = 0.f, s1 = 0.f;
                #pragma unroll
                for (int cr = 0; cr < 4; ++cr) {
                    unsigned int v = *(const unsigned int*)(xtb + (size_t)id[cr] * CIN + 2 * l);
                    float c0v, c1v;
                    unsigned int lo = v << 16, hi = v & 0xffff0000u;
                    __builtin_memcpy(&c0v, &lo, 4);
                    __builtin_memcpy(&c1v, &hi, 4);
                    float gf = (float)gh[cr];
                    s0 += gf * c0v;
                    s1 += gf * c1v;
                }
                bf16x2 pr = { (__bf16)s0, (__bf16)s1 };
                *(bf16x2*)&Bt[p][tap_l * CIN + 2 * l] = pr;
            }
        } else {
            for (int dd = 0; dd < KSC; ++dd) {
                int dl = wv * KSC + dd;
                int tap_l = dl >> 5, p = dl & 31;
                int d = t * 96 + dl;
                ushort4v id = *(const ushort4v*)&sIdxP[d][0];
                half4v   gh = *(const half4v*)&sGP[d][0];
                float s0 = 0.f, s1 = 0.f;
                #pragma unroll
                for (int cr = 0; cr < 4; ++cr) {
                    float gf = (float)gh[cr];
                    s0 += gf * xb[((size_t)(2 * l) << 12) + id[cr]];
                    s1 += gf * xb[((size_t)(2 * l + 1) << 12) + id[cr]];
                }
                bf16x2 pr = { (__bf16)s0, (__bf16)s1 };
                *(bf16x2*)&Bt[p][tap_l * CIN + 2 * l] = pr;
            }
        }
        __syncthreads();

        #pragma unroll 4
        for (int ks = 0; ks < KSC; ++ks) {
            int ks_g = t * KSC + ks;
            v8bf16 bfrag = *(const v8bf16*)(brow + ks * 32);
            v8bf16 afrag;
            if (mode >= 1) {
                afrag = *(const v8bf16*)(wfrag + (((size_t)ot * KSTEPS + ks_g) * 64 + l) * 8);
            } else {
                int o = ot * 16 + lr;
                #pragma unroll
                for (int e = 0; e < 8; ++e) {
                    int k = ks_g * 32 + quad * 8 + e;
                    int tap = k >> 7, c = k & 127;
                    afrag[e] = (__bf16)w[(size_t)o * KTOT + c * NPT + tap];
                }
            }
            acc = __builtin_amdgcn_mfma_f32_16x16x32_bf16(afrag, bfrag, acc, 0, 0, 0);
        }
        if (t < 2) __syncthreads();
    }

    {
        int obase = ot * 16 + quad * 4;
        float* op = out + (((size_t)(b * OC + obase)) << 12) + (i << 6) + j0 + ph * 16 + lr;
        #pragma unroll
        for (int r = 0; r < 4; ++r)
            op[(size_t)r << 12] = acc[r];
    }
}

extern "C" void kernel_launch(void* const* d_in, const int* in_sizes, int n_in,
                              void* d_out, int out_size, void* d_ws, size_t ws_size,
                              hipStream_t stream) {
    const float* x   = (const float*)d_in[0];
    const float* off = (const float*)d_in[1];
    const float* w   = (const float*)d_in[2];
    float* out = (float*)d_out;

    const size_t wfrag_bytes = (size_t)OC * KTOT * sizeof(__bf16);        // 294912
    const size_t xt_bytes    = (size_t)4 * 4096 * CIN * sizeof(__bf16);   // 4 MB
    const size_t desc_bytes  = (size_t)DTOT * 16;                         // 2.36 MB
    const size_t part_bytes  = (size_t)2 * 4 * OC * 4096 * sizeof(float); // 16.8 MB

    int mode = 0;
    if (ws_size >= wfrag_bytes + xt_bytes + desc_bytes + part_bytes) mode = 3;
    else if (ws_size >= wfrag_bytes + xt_bytes) mode = 2;
    else if (ws_size >= wfrag_bytes) mode = 1;

    __bf16* wfrag = (__bf16*)d_ws;
    __bf16* xt    = (__bf16*)((char*)d_ws + wfrag_bytes);
    uint4*  desc  = (uint4*) ((char*)d_ws + wfrag_bytes + xt_bytes);
    float*  part  = (float*) ((char*)d_ws + wfrag_bytes + xt_bytes + desc_bytes);

    if (mode >= 1)
        wfrag_kernel<<<(8 * KSTEPS * 64 + 255) / 256, 256, 0, stream>>>(w, wfrag);
    if (mode >= 2)
        xpose_kernel<<<4 * 64 * 4, 256, 0, stream>>>(x, xt);

    if (mode == 3) {
        desc_kernel<<<(DTOT + 255) / 256, 256, 0, stream>>>(off, desc);
        splitk_kernel<<<1024, 512, 0, stream>>>(desc, xt, wfrag, part);
        reduce_kernel<<<2048, 256, 0, stream>>>(part, out);
    } else {
        deform_fused_kernel<<<4 * 64 * 2 * 2, 512, 0, stream>>>(x, off, w, wfrag, xt, out, mode);
    }
}

// Round 8
// 94.200 us; speedup vs baseline: 1.1787x; 1.1225x over previous
//
#include <hip/hip_runtime.h>

// DeformConv2D b=4,c=128,H=W=64,outc=128,KS=3,PAD=1,N=9
// Split-K=3 full-row pipeline (mode 3):
//   1) xpose : x NCHW fp32 -> xt (b,hw,c) bf16
//   2) wfrag : weight -> MFMA A-frag layout [ot][ks][lane][8]
//   3) desck : 147456 sample descriptors (idx4 u16 + g4 f16, 16B each)
//   4) splitk: grid 768 = b4*i64*kh3, block = 64px x 128o, taps 3kh..3kh+2.
//              wave = 16-o tile x 64 px: 1 afrag -> 4 MFMAs (4 px quarters).
//   5) reduce: out = p0 + p1 + p2
// Fallback (mode<=2): round-5 fused kernel (verified).

typedef __bf16  v8bf16 __attribute__((ext_vector_type(8)));
typedef __bf16  bf16x2 __attribute__((ext_vector_type(2)));
typedef float   f32x4  __attribute__((ext_vector_type(4)));
typedef unsigned short ushort4v __attribute__((ext_vector_type(4)));
typedef _Float16 half4v __attribute__((ext_vector_type(4)));

#define CIN  128
#define NPT  9
#define KTOT 1152
#define OC   128
#define PX   32
#define NDESC (NPT * PX)
#define KSTEPS 36
#define KSC  12
#define LDBc 392
#define DTOT (9 * 4 * 64 * 64)   // 147456
#define PXR  64                  // full row
#define LDR  392                 // 3*128+8

// ---------- x NCHW fp32 -> channels-last bf16 ----------
__global__ __launch_bounds__(256) void xpose_kernel(const float* __restrict__ x,
                                                    __bf16* __restrict__ xt) {
    __shared__ float tile[64][33];
    const int bidx = blockIdx.x;
    const int b   = bidx >> 8;
    const int hw0 = ((bidx >> 2) & 63) * 64;
    const int c0  = (bidx & 3) * 32;
    const int tid = threadIdx.x;
    #pragma unroll
    for (int r = 0; r < 8; ++r) {
        int c_l  = (tid >> 6) + r * 4;
        int hw_l = tid & 63;
        tile[hw_l][c_l] = x[((size_t)(b * CIN + c0 + c_l) << 12) + hw0 + hw_l];
    }
    __syncthreads();
    #pragma unroll
    for (int r = 0; r < 8; ++r) {
        int hw_l = (tid >> 5) + r * 8;
        int c_l  = tid & 31;
        xt[((size_t)(b * 4096 + hw0 + hw_l)) * CIN + c0 + c_l] = (__bf16)tile[hw_l][c_l];
    }
}

// ---------- weight -> A-fragment layout ----------
__global__ __launch_bounds__(256) void wfrag_kernel(const float* __restrict__ w,
                                                    __bf16* __restrict__ wfrag) {
    int t = blockIdx.x * 256 + threadIdx.x;
    if (t >= 8 * KSTEPS * 64) return;
    int lane = t & 63;
    int ks   = (t >> 6) % KSTEPS;
    int ot   = t / (KSTEPS * 64);
    int o    = ot * 16 + (lane & 15);
    v8bf16 frag;
    #pragma unroll
    for (int e = 0; e < 8; ++e) {
        int k   = ks * 32 + (lane >> 4) * 8 + e;
        int tap = k >> 7, c = k & 127;
        frag[e] = (__bf16)w[(size_t)o * KTOT + c * NPT + tap];
    }
    *(v8bf16*)(wfrag + (size_t)t * 8) = frag;
}

// ---------- descriptor kernel: one thread per (tap,b,i,j) ----------
__global__ __launch_bounds__(256) void desc_kernel(const float* __restrict__ off,
                                                   uint4* __restrict__ desc) {
    int t = blockIdx.x * 256 + threadIdx.x;
    if (t >= DTOT) return;
    int j   = t & 63;
    int i   = (t >> 6) & 63;
    int b   = (t >> 12) & 3;
    int tap = t >> 14;

    float ox = off[(((b * 18) + 2 * tap) << 12) + (i << 6) + j];
    float oy = off[(((b * 18) + 2 * tap + 1) << 12) + (i << 6) + j];
    float px = (float)(i + tap / 3) + ox;
    float py = (float)(j + tap % 3) + oy;
    float fx = floorf(px), fy = floorf(py);
    int qltx = (int)fminf(fmaxf(fx, 0.f), 65.f);
    int qlty = (int)fminf(fmaxf(fy, 0.f), 65.f);
    int qrbx = (int)fminf(fmaxf(fx + 1.f, 0.f), 65.f);
    int qrby = (int)fminf(fmaxf(fy + 1.f, 0.f), 65.f);
    if (px < 1.f || px > 64.f) px = fx;
    if (py < 1.f || py > 64.f) py = fy;
    px = fminf(fmaxf(px, 0.f), 65.f);
    py = fminf(fmaxf(py, 0.f), 65.f);
    float wxl = 1.f + (float)qltx - px;
    float wxr = 1.f - ((float)qrbx - px);
    float wyl = 1.f + (float)qlty - py;
    float wyr = 1.f - ((float)qrby - py);
    float g[4] = { wxl * wyl, wxr * wyr, wxl * wyr, wxr * wyl };
    int qx[4] = { qltx, qrbx, qltx, qrbx };
    int qy[4] = { qlty, qrby, qrby, qlty };
    unsigned short idx[4];
    half4v gh;
    #pragma unroll
    for (int cr = 0; cr < 4; ++cr) {
        bool inb = (qx[cr] >= 1) && (qx[cr] <= 64) && (qy[cr] >= 1) && (qy[cr] <= 64);
        idx[cr] = inb ? (unsigned short)((qx[cr] - 1) * 64 + (qy[cr] - 1)) : 0;
        gh[cr]  = inb ? (_Float16)g[cr] : (_Float16)0.f;
    }
    uint4 rec;
    rec.x = (unsigned)idx[0] | ((unsigned)idx[1] << 16);
    rec.y = (unsigned)idx[2] | ((unsigned)idx[3] << 16);
    __builtin_memcpy(&rec.z, &gh, 8);
    int d = (((b << 6) + i) * 64 + j) * 9 + tap;
    desc[d] = rec;
}

// ---------- split-K=3 full-row kernel ----------
__global__ __launch_bounds__(512, 6) void splitk_kernel(
    const uint4* __restrict__ desc, const __bf16* __restrict__ xt,
    const __bf16* __restrict__ wfrag, float* __restrict__ part)
{
    __shared__ __align__(16) __bf16 Bt[PXR][LDR];   // 50176 B

    const int bidx = blockIdx.x;     // 768 = b(4) * i(64) * kh(3)
    const int kh  = bidx & 3 ? 0 : 0; // placeholder (computed below)
    const int kh3 = bidx % 3;
    const int rest = bidx / 3;
    const int i   = rest & 63;
    const int b   = rest >> 6;
    const int tid = threadIdx.x;
    (void)kh;

    const int tap0 = kh3 * 3;

    const int l  = tid & 63;
    const int wv = tid >> 6;            // 0..7

    const __bf16* xtb = xt + (((size_t)b << 12) * CIN);
    const int pix_base = ((b << 6) + i) * 64;

    // ---- stage: 192 descs (3 taps x 64 px), 24 per wave ----
    #pragma unroll 4
    for (int dd = 0; dd < 24; ++dd) {
        int dl = wv * 24 + dd;          // [0,192)
        int tap_l = dl >> 6, p = dl & 63;
        int d = (pix_base + p) * 9 + tap0 + tap_l;
        uint4 q = desc[d];
        unsigned short idx[4] = { (unsigned short)(q.x & 0xffff), (unsigned short)(q.x >> 16),
                                  (unsigned short)(q.y & 0xffff), (unsigned short)(q.y >> 16) };
        half4v gh;
        __builtin_memcpy(&gh, &q.z, 8);
        float s0 = 0.f, s1 = 0.f;
        #pragma unroll
        for (int cr = 0; cr < 4; ++cr) {
            unsigned int v = *(const unsigned int*)(xtb + (size_t)idx[cr] * CIN + 2 * l);
            float c0v, c1v;
            unsigned int lo = v << 16, hi = v & 0xffff0000u;
            __builtin_memcpy(&c0v, &lo, 4);
            __builtin_memcpy(&c1v, &hi, 4);
            float gf = (float)gh[cr];
            s0 += gf * c0v;
            s1 += gf * c1v;
        }
        bf16x2 pr = { (__bf16)s0, (__bf16)s1 };
        *(bf16x2*)&Bt[p][tap_l * CIN + 2 * l] = pr;
    }
    __syncthreads();

    // ---- MFMA: wave = ot (wv), 4 px-quarters share each afrag ----
    const int quad = l >> 4;
    const int lr   = l & 15;

    f32x4 acc0 = {0.f, 0.f, 0.f, 0.f};
    f32x4 acc1 = {0.f, 0.f, 0.f, 0.f};
    f32x4 acc2 = {0.f, 0.f, 0.f, 0.f};
    f32x4 acc3 = {0.f, 0.f, 0.f, 0.f};

    const __bf16* brow0 = &Bt[lr][quad * 8];
    const __bf16* brow1 = &Bt[16 + lr][quad * 8];
    const __bf16* brow2 = &Bt[32 + lr][quad * 8];
    const __bf16* brow3 = &Bt[48 + lr][quad * 8];

    #pragma unroll 3
    for (int ks = 0; ks < KSC; ++ks) {
        int ks_g = kh3 * KSC + ks;
        v8bf16 afrag = *(const v8bf16*)(wfrag + (((size_t)wv * KSTEPS + ks_g) * 64 + l) * 8);
        v8bf16 b0 = *(const v8bf16*)(brow0 + ks * 32);
        v8bf16 b1 = *(const v8bf16*)(brow1 + ks * 32);
        v8bf16 b2 = *(const v8bf16*)(brow2 + ks * 32);
        v8bf16 b3 = *(const v8bf16*)(brow3 + ks * 32);
        acc0 = __builtin_amdgcn_mfma_f32_16x16x32_bf16(afrag, b0, acc0, 0, 0, 0);
        acc1 = __builtin_amdgcn_mfma_f32_16x16x32_bf16(afrag, b1, acc1, 0, 0, 0);
        acc2 = __builtin_amdgcn_mfma_f32_16x16x32_bf16(afrag, b2, acc2, 0, 0, 0);
        acc3 = __builtin_amdgcn_mfma_f32_16x16x32_bf16(afrag, b3, acc3, 0, 0, 0);
    }

    // ---- epilogue -> partials[kh3] ----
    float* pc = part + ((size_t)kh3 << 21);
    int obase = wv * 16 + quad * 4;
    float* opb = pc + (((size_t)(b * OC + obase)) << 12) + (i << 6) + lr;
    #pragma unroll
    for (int ph = 0; ph < 4; ++ph) {
        f32x4 a = (ph == 0) ? acc0 : (ph == 1) ? acc1 : (ph == 2) ? acc2 : acc3;
        float* op = opb + ph * 16;
        #pragma unroll
        for (int r = 0; r < 4; ++r)
            op[(size_t)r << 12] = a[r];
    }
}

// ---------- reduce: out = p0 + p1 + p2 ----------
__global__ __launch_bounds__(256) void reduce_kernel(const float* __restrict__ part,
                                                     float* __restrict__ out) {
    int t = blockIdx.x * 256 + threadIdx.x;   // 524288 threads, float4 each
    f32x4 a = *(const f32x4*)(part + (size_t)t * 4);
    f32x4 c = *(const f32x4*)(part + (1u << 21) + (size_t)t * 4);
    f32x4 d = *(const f32x4*)(part + (2u << 21) + (size_t)t * 4);
    f32x4 r = a + c + d;
    *(f32x4*)(out + (size_t)t * 4) = r;
}

// ---------- round-5 fused fallback (verified) ----------
__global__ __launch_bounds__(512, 8) void deform_fused_kernel(
    const float* __restrict__ x, const float* __restrict__ off,
    const float* __restrict__ w, const __bf16* __restrict__ wfrag,
    const __bf16* __restrict__ xt, float* __restrict__ out, int mode)
{
    __shared__ __align__(16) __bf16 Bt[PX][LDBc];
    __shared__ __align__(8)  unsigned short sIdxP[NDESC][4];
    __shared__ __align__(8)  _Float16      sGP[NDESC][4];

    const int bidx = blockIdx.x;
    const int b   = bidx >> 8;
    const int i   = (bidx >> 2) & 63;
    const int j0  = ((bidx >> 1) & 1) * PX;
    const int oh  = bidx & 1;
    const int tid = threadIdx.x;

    if (tid < NDESC) {
        int k = tid >> 5, p = tid & 31;
        int j = j0 + p;
        float ox = off[(((b * 18) + 2 * k) * 64 + i) * 64 + j];
        float oy = off[(((b * 18) + 2 * k + 1) * 64 + i) * 64 + j];
        float px = (float)(i + k / 3) + ox;
        float py = (float)(j + k % 3) + oy;
        float fx = floorf(px), fy = floorf(py);
        int qltx = (int)fminf(fmaxf(fx, 0.f), 65.f);
        int qlty = (int)fminf(fmaxf(fy, 0.f), 65.f);
        int qrbx = (int)fminf(fmaxf(fx + 1.f, 0.f), 65.f);
        int qrby = (int)fminf(fmaxf(fy + 1.f, 0.f), 65.f);
        if (px < 1.f || px > 64.f) px = fx;
        if (py < 1.f || py > 64.f) py = fy;
        px = fminf(fmaxf(px, 0.f), 65.f);
        py = fminf(fmaxf(py, 0.f), 65.f);
        float wxl = 1.f + (float)qltx - px;
        float wxr = 1.f - ((float)qrbx - px);
        float wyl = 1.f + (float)qlty - py;
        float wyr = 1.f - ((float)qrby - py);
        float g[4] = { wxl * wyl, wxr * wyr, wxl * wyr, wxr * wyl };
        int qx[4] = { qltx, qrbx, qltx, qrbx };
        int qy[4] = { qlty, qrby, qrby, qlty };
        #pragma unroll
        for (int cr = 0; cr < 4; ++cr) {
            bool inb = (qx[cr] >= 1) && (qx[cr] <= 64) && (qy[cr] >= 1) && (qy[cr] <= 64);
            sIdxP[tid][cr] = inb ? (unsigned short)((qx[cr] - 1) * 64 + (qy[cr] - 1)) : 0;
            sGP[tid][cr]   = inb ? (_Float16)g[cr] : (_Float16)0.f;
        }
    }
    __syncthreads();

    const int l    = tid & 63;
    const int wv   = tid >> 6;
    const int ot   = oh * 4 + (wv & 3);
    const int ph   = wv >> 2;
    const int quad = l >> 4;
    const int lr   = l & 15;

    f32x4 acc = {0.f, 0.f, 0.f, 0.f};
    const __bf16* xtb = xt + ((size_t)b * 4096) * CIN;
    const float*  xb  = x + ((size_t)b * CIN << 12);
    const __bf16* brow = &Bt[ph * 16 + lr][quad * 8];

    for (int t = 0; t < 3; ++t) {
        if (mode == 2) {
            #pragma unroll 4
            for (int dd = 0; dd < KSC; ++dd) {
                int dl = wv * KSC + dd;
                int tap_l = dl >> 5, p = dl & 31;
                int d = t * 96 + dl;
                ushort4v id = *(const ushort4v*)&sIdxP[d][0];
                half4v   gh = *(const half4v*)&sGP[d][0];
                float s0 = 0.f, s1 = 0.f;
                #pragma unroll
                for (int cr = 0; cr < 4; ++cr) {
                    unsigned int v = *(const unsigned int*)(xtb + (size_t)id[cr] * CIN + 2 * l);
                    float c0v, c1v;
                    unsigned int lo = v << 16, hi = v & 0xffff0000u;
                    __builtin_memcpy(&c0v, &lo, 4);
                    __builtin_memcpy(&c1v, &hi, 4);
                    float gf = (float)gh[cr];
                    s0 += gf * c0v;
                    s1 += gf * c1v;
                }
                bf16x2 pr = { (__bf16)s0, (__bf16)s1 };
                *(bf16x2*)&Bt[p][tap_l * CIN + 2 * l] = pr;
            }
        } else {
            for (int dd = 0; dd < KSC; ++dd) {
                int dl = wv * KSC + dd;
                int tap_l = dl >> 5, p = dl & 31;
                int d = t * 96 + dl;
                ushort4v id = *(const ushort4v*)&sIdxP[d][0];
                half4v   gh = *(const half4v*)&sGP[d][0];
                float s0 = 0.f, s1 = 0.f;
                #pragma unroll
                for (int cr = 0; cr < 4; ++cr) {
                    float gf = (float)gh[cr];
                    s0 += gf * xb[((size_t)(2 * l) << 12) + id[cr]];
                    s1 += gf * xb[((size_t)(2 * l + 1) << 12) + id[cr]];
                }
                bf16x2 pr = { (__bf16)s0, (__bf16)s1 };
                *(bf16x2*)&Bt[p][tap_l * CIN + 2 * l] = pr;
            }
        }
        __syncthreads();

        #pragma unroll 4
        for (int ks = 0; ks < KSC; ++ks) {
            int ks_g = t * KSC + ks;
            v8bf16 bfrag = *(const v8bf16*)(brow + ks * 32);
            v8bf16 afrag;
            if (mode >= 1) {
                afrag = *(const v8bf16*)(wfrag + (((size_t)ot * KSTEPS + ks_g) * 64 + l) * 8);
            } else {
                int o = ot * 16 + lr;
                #pragma unroll
                for (int e = 0; e < 8; ++e) {
                    int k = ks_g * 32 + quad * 8 + e;
                    int tap = k >> 7, c = k & 127;
                    afrag[e] = (__bf16)w[(size_t)o * KTOT + c * NPT + tap];
                }
            }
            acc = __builtin_amdgcn_mfma_f32_16x16x32_bf16(afrag, bfrag, acc, 0, 0, 0);
        }
        if (t < 2) __syncthreads();
    }

    {
        int obase = ot * 16 + quad * 4;
        float* op = out + (((size_t)(b * OC + obase)) << 12) + (i << 6) + j0 + ph * 16 + lr;
        #pragma unroll
        for (int r = 0; r < 4; ++r)
            op[(size_t)r << 12] = acc[r];
    }
}

extern "C" void kernel_launch(void* const* d_in, const int* in_sizes, int n_in,
                              void* d_out, int out_size, void* d_ws, size_t ws_size,
                              hipStream_t stream) {
    const float* x   = (const float*)d_in[0];
    const float* off = (const float*)d_in[1];
    const float* w   = (const float*)d_in[2];
    float* out = (float*)d_out;

    const size_t wfrag_bytes = (size_t)OC * KTOT * sizeof(__bf16);        // 294912
    const size_t xt_bytes    = (size_t)4 * 4096 * CIN * sizeof(__bf16);   // 4 MB
    const size_t desc_bytes  = (size_t)DTOT * 16;                         // 2.36 MB
    const size_t part_bytes  = (size_t)3 * 4 * OC * 4096 * sizeof(float); // 25.2 MB

    int mode = 0;
    if (ws_size >= wfrag_bytes + xt_bytes + desc_bytes + part_bytes) mode = 3;
    else if (ws_size >= wfrag_bytes + xt_bytes) mode = 2;
    else if (ws_size >= wfrag_bytes) mode = 1;

    __bf16* wfrag = (__bf16*)d_ws;
    __bf16* xt    = (__bf16*)((char*)d_ws + wfrag_bytes);
    uint4*  desc  = (uint4*) ((char*)d_ws + wfrag_bytes + xt_bytes);
    float*  part  = (float*) ((char*)d_ws + wfrag_bytes + xt_bytes + desc_bytes);

    if (mode >= 1)
        wfrag_kernel<<<(8 * KSTEPS * 64 + 255) / 256, 256, 0, stream>>>(w, wfrag);
    if (mode >= 2)
        xpose_kernel<<<4 * 64 * 4, 256, 0, stream>>>(x, xt);

    if (mode == 3) {
        desc_kernel<<<(DTOT + 255) / 256, 256, 0, stream>>>(off, desc);
        splitk_kernel<<<4 * 64 * 3, 512, 0, stream>>>(desc, xt, wfrag, part);
        reduce_kernel<<<2048, 256, 0, stream>>>(part, out);
    } else {
        deform_fused_kernel<<<4 * 64 * 2 * 2, 512, 0, stream>>>(x, off, w, wfrag, xt, out, mode);
    }
}